// Round 2
// baseline (1167.105 us; speedup 1.0000x reference)
//
#include <hip/hip_runtime.h>
#include <stdint.h>

#define DIM 16
#define HID 128
#define TN  64            // nodes per block
#define ROWF 132          // LDS row stride in floats (128 + 4 pad)
#define EPSF 1e-5f

typedef unsigned int u32;

// NaN-free tanh; |x| <= ~12 here (LN output bounded by sqrt(H))
__device__ __forceinline__ float safe_tanh(float x) {
    float a = fabsf(x);
    float e = __expf(2.0f * a);
    float t = 1.0f - 2.0f / (e + 1.0f);
    return copysignf(t, x);
}

// ---------------- CSR path ------------------------------------------------
// deg/off/cur are concatenated over both directions:
//   index i in [0,N)    -> in-degree of node i (list keyed by dst)
//   index N+i           -> out-degree of node i (list keyed by src)
// One exclusive scan over 2N gives both offset tables; in-lists occupy
// lists[0,E), out-lists lists[E,2E) automatically (sum of in-degrees == E).

__global__ void __launch_bounds__(256) hist_kernel(
    const int* __restrict__ edges, u32* __restrict__ deg, int nEdges, int N)
{
    int e = blockIdx.x * 256 + threadIdx.x;
    if (e >= nEdges) return;
    int src = edges[2 * e];
    int dst = edges[2 * e + 1];
    atomicAdd(&deg[dst], 1u);        // in-degree
    atomicAdd(&deg[N + src], 1u);    // out-degree
}

// per-256-block sums of deg -> bsum
__global__ void __launch_bounds__(256) scan_block_sums(
    const u32* __restrict__ deg, u32* __restrict__ bsum, int total)
{
    int i = blockIdx.x * 256 + threadIdx.x;
    u32 v = (i < total) ? deg[i] : 0u;
    #pragma unroll
    for (int m = 1; m <= 32; m <<= 1) v += __shfl_xor(v, m);
    __shared__ u32 ws[4];
    if ((threadIdx.x & 63) == 0) ws[threadIdx.x >> 6] = v;
    __syncthreads();
    if (threadIdx.x == 0) bsum[blockIdx.x] = ws[0] + ws[1] + ws[2] + ws[3];
}

// exclusive scan of bsum in place (single block, chunked, any nb)
__global__ void __launch_bounds__(1024) scan_carry(u32* __restrict__ bsum, int nb)
{
    __shared__ u32 sm[1024];
    const int tid = threadIdx.x;
    u32 carry = 0;
    for (int base = 0; base < nb; base += 1024) {
        int i = base + tid;
        u32 v = (i < nb) ? bsum[i] : 0u;
        __syncthreads();               // protect sm[1023] reads from prev iter
        sm[tid] = v;
        __syncthreads();
        for (int s = 1; s < 1024; s <<= 1) {
            u32 t = (tid >= s) ? sm[tid - s] : 0u;
            __syncthreads();
            sm[tid] += t;
            __syncthreads();
        }
        u32 inc = sm[tid];
        if (i < nb) bsum[i] = inc - v + carry;   // exclusive + carry
        carry += sm[1023];
    }
}

// final: off[i] = block-exclusive-scan + bsum[block]; cur = copy of off
__global__ void __launch_bounds__(256) scan_final(
    const u32* __restrict__ deg, const u32* __restrict__ bsum,
    u32* __restrict__ off, u32* __restrict__ cur, int total)
{
    __shared__ u32 sm[256];
    const int tid = threadIdx.x;
    int i = blockIdx.x * 256 + tid;
    u32 v = (i < total) ? deg[i] : 0u;
    sm[tid] = v;
    __syncthreads();
    for (int s = 1; s < 256; s <<= 1) {
        u32 t = (tid >= s) ? sm[tid - s] : 0u;
        __syncthreads();
        sm[tid] += t;
        __syncthreads();
    }
    u32 excl = sm[tid] - v + bsum[blockIdx.x];
    if (i < total) { off[i] = excl; cur[i] = excl; }
}

// scatter edge records into adjacency lists via cursor bump
__global__ void __launch_bounds__(256) fill_kernel(
    const int* __restrict__ edges, const float* __restrict__ ew,
    u32* __restrict__ cur, uint2* __restrict__ lists, int nEdges, int N)
{
    int e = blockIdx.x * 256 + threadIdx.x;
    if (e >= nEdges) return;
    int src = edges[2 * e];
    int dst = edges[2 * e + 1];
    u32 wbits = __float_as_uint(ew[e]);
    u32 s1 = atomicAdd(&cur[dst], 1u);          // in-list of dst: neighbor=src
    lists[s1] = make_uint2((u32)src, wbits);
    u32 s2 = atomicAdd(&cur[N + src], 1u);      // out-list of src: neighbor=dst
    lists[s2] = make_uint2((u32)dst, wbits);
}

// per-node sequential sums; 16 lanes per node (lane = component)
__global__ void __launch_bounds__(256) gather_kernel(
    const float* __restrict__ nodes, const uint2* __restrict__ lists,
    const u32* __restrict__ off, const u32* __restrict__ deg,
    float* __restrict__ agg_in, float* __restrict__ agg_out, int N)
{
    int t = blockIdx.x * 256 + threadIdx.x;
    int n = t >> 4;
    int c = t & 15;
    if (n >= N) return;

    // in-list
    {
        u32 o = off[n], d = deg[n];
        float acc = 0.f;
        u32 k = 0;
        for (; k + 2 <= d; k += 2) {
            uint2 e0 = lists[o + k];
            uint2 e1 = lists[o + k + 1];
            acc += nodes[e0.x * DIM + c] * __uint_as_float(e0.y);
            acc += nodes[e1.x * DIM + c] * __uint_as_float(e1.y);
        }
        if (k < d) {
            uint2 e0 = lists[o + k];
            acc += nodes[e0.x * DIM + c] * __uint_as_float(e0.y);
        }
        agg_in[(size_t)n * DIM + c] = acc;
    }
    // out-list
    {
        u32 o = off[N + n], d = deg[N + n];
        float acc = 0.f;
        u32 k = 0;
        for (; k + 2 <= d; k += 2) {
            uint2 e0 = lists[o + k];
            uint2 e1 = lists[o + k + 1];
            acc += nodes[e0.x * DIM + c] * __uint_as_float(e0.y);
            acc += nodes[e1.x * DIM + c] * __uint_as_float(e1.y);
        }
        if (k < d) {
            uint2 e0 = lists[o + k];
            acc += nodes[e0.x * DIM + c] * __uint_as_float(e0.y);
        }
        agg_out[(size_t)n * DIM + c] = acc;
    }
}

// ---------------- fallback: fp32 atomic scatter (round-0, verified) -------
__global__ void __launch_bounds__(256) edge_scatter_fallback(
    const float* __restrict__ nodes, const int* __restrict__ edges,
    const float* __restrict__ ew, float* __restrict__ agg_in,
    float* __restrict__ agg_out, int nEdges)
{
    int gid = blockIdx.x * 256 + threadIdx.x;
    int e = gid >> 4;
    if (e >= nEdges) return;
    int c = gid & 15;
    int src = edges[2 * e];
    int dst = edges[2 * e + 1];
    float w  = ew[e];
    float vs = nodes[src * DIM + c];
    float vd = nodes[dst * DIM + c];
    atomicAdd(&agg_in[dst * DIM + c], vs * w);
    atomicAdd(&agg_out[src * DIM + c], vd * w);
}

// ---------------- Phase 2: fused 4-layer MLP (round-0, verified) ----------
template<int K>
__device__ __forceinline__ void dense_ln_tanh(
    const float* __restrict__ W, const float* __restrict__ bias,
    const float* __restrict__ g, const float* __restrict__ be,
    float (&X)[TN][ROWF], int tid)
{
    const int c0 = (tid & 31) * 4;   // column group: lanes 0..31 cover 128 cols
    const int n0 = (tid >> 5) * 8;   // row group: 8 rows per thread
    float acc[8][4];
    {
        float4 bv = *(const float4*)(bias + c0);
        #pragma unroll
        for (int i = 0; i < 8; ++i) {
            acc[i][0] = bv.x; acc[i][1] = bv.y; acc[i][2] = bv.z; acc[i][3] = bv.w;
        }
    }

    #pragma unroll 2
    for (int k = 0; k < K; k += 4) {
        float xr[8][4];
        #pragma unroll
        for (int i = 0; i < 8; ++i) {
            float4 t = *(const float4*)&X[n0 + i][k];
            xr[i][0] = t.x; xr[i][1] = t.y; xr[i][2] = t.z; xr[i][3] = t.w;
        }
        float w[4][4];
        #pragma unroll
        for (int kk = 0; kk < 4; ++kk) {
            float4 t = *(const float4*)(W + (k + kk) * HID + c0);
            w[kk][0] = t.x; w[kk][1] = t.y; w[kk][2] = t.z; w[kk][3] = t.w;
        }
        #pragma unroll
        for (int kk = 0; kk < 4; ++kk)
            #pragma unroll
            for (int i = 0; i < 8; ++i)
                #pragma unroll
                for (int j = 0; j < 4; ++j) acc[i][j] += xr[i][kk] * w[kk][j];
    }

    float s[8], q[8];
    #pragma unroll
    for (int i = 0; i < 8; ++i) {
        s[i] = acc[i][0] + acc[i][1] + acc[i][2] + acc[i][3];
        q[i] = acc[i][0]*acc[i][0] + acc[i][1]*acc[i][1]
             + acc[i][2]*acc[i][2] + acc[i][3]*acc[i][3];
    }
    #pragma unroll
    for (int m = 1; m <= 16; m <<= 1) {
        #pragma unroll
        for (int i = 0; i < 8; ++i) {
            s[i] += __shfl_xor(s[i], m);
            q[i] += __shfl_xor(q[i], m);
        }
    }

    float4 gv  = *(const float4*)(g + c0);
    float4 bev = *(const float4*)(be + c0);
    float gr[4]  = {gv.x, gv.y, gv.z, gv.w};
    float ber[4] = {bev.x, bev.y, bev.z, bev.w};

    __syncthreads();   // all X reads of this layer complete before overwrite
    #pragma unroll
    for (int i = 0; i < 8; ++i) {
        float mean = s[i] * (1.0f / HID);
        float var  = fmaxf(q[i] * (1.0f / HID) - mean * mean, 0.0f);
        float r = rsqrtf(var + EPSF);
        float o[4];
        #pragma unroll
        for (int j = 0; j < 4; ++j)
            o[j] = safe_tanh((acc[i][j] - mean) * r * gr[j] + ber[j]);
        *(float4*)&X[n0 + i][c0] = make_float4(o[0], o[1], o[2], o[3]);
    }
    __syncthreads();
}

__global__ void __launch_bounds__(256, 3) mlp_kernel(
    const float* __restrict__ agg_in, const float* __restrict__ agg_out,
    const float* __restrict__ nodes,
    const float* __restrict__ W1, const float* __restrict__ b1, const float* __restrict__ g1, const float* __restrict__ be1,
    const float* __restrict__ W2, const float* __restrict__ b2, const float* __restrict__ g2, const float* __restrict__ be2,
    const float* __restrict__ W3, const float* __restrict__ b3, const float* __restrict__ g3, const float* __restrict__ be3,
    const float* __restrict__ W4, const float* __restrict__ b4, const float* __restrict__ g4, const float* __restrict__ be4,
    float* __restrict__ out, int nNodes)
{
    __shared__ float X[TN][ROWF];

    const int tid = threadIdx.x;
    const int node0 = blockIdx.x * TN;

    // stage x = concat(agg_in, agg_out, nodes): 64 rows x 12 float4
    for (int i = tid; i < TN * 12; i += 256) {
        int n = i / 12, c4 = i - n * 12;
        int gn = node0 + n;
        float4 v = make_float4(0.f, 0.f, 0.f, 0.f);
        if (gn < nNodes) {
            if (c4 < 4)      v = *(const float4*)(agg_in  + (size_t)gn * DIM + c4 * 4);
            else if (c4 < 8) v = *(const float4*)(agg_out + (size_t)gn * DIM + (c4 - 4) * 4);
            else             v = *(const float4*)(nodes   + (size_t)gn * DIM + (c4 - 8) * 4);
        }
        *(float4*)&X[n][c4 * 4] = v;
    }
    __syncthreads();

    dense_ln_tanh<48>(W1, b1, g1, be1, X, tid);
    dense_ln_tanh<128>(W2, b2, g2, be2, X, tid);
    dense_ln_tanh<128>(W3, b3, g3, be3, X, tid);

    // Layer 4: 128 -> 16, LN over 16, tanh, store fp32
    {
        const int c2 = tid & 15;
        const int nb = tid >> 4;   // 0..15; handles nodes nb + {0,16,32,48}
        float a[4];
        {
            float bv = b4[c2];
            #pragma unroll
            for (int t = 0; t < 4; ++t) a[t] = bv;
        }
        #pragma unroll 2
        for (int k = 0; k < HID; k += 4) {
            float w[4];
            #pragma unroll
            for (int kk = 0; kk < 4; ++kk) w[kk] = W4[(k + kk) * DIM + c2];
            #pragma unroll
            for (int t = 0; t < 4; ++t) {
                float4 x = *(const float4*)&X[nb + 16 * t][k];
                a[t] += x.x * w[0] + x.y * w[1] + x.z * w[2] + x.w * w[3];
            }
        }
        float s[4], q[4];
        #pragma unroll
        for (int t = 0; t < 4; ++t) { s[t] = a[t]; q[t] = a[t] * a[t]; }
        #pragma unroll
        for (int m = 1; m <= 8; m <<= 1) {
            #pragma unroll
            for (int t = 0; t < 4; ++t) {
                s[t] += __shfl_xor(s[t], m);
                q[t] += __shfl_xor(q[t], m);
            }
        }
        float g4v = g4[c2], be4v = be4[c2];
        #pragma unroll
        for (int t = 0; t < 4; ++t) {
            int node = node0 + nb + 16 * t;
            if (node < nNodes) {
                float mean = s[t] * (1.0f / DIM);
                float var  = fmaxf(q[t] * (1.0f / DIM) - mean * mean, 0.0f);
                float o = safe_tanh((a[t] - mean) * rsqrtf(var + EPSF) * g4v + be4v);
                out[(size_t)node * DIM + c2] = o;
            }
        }
    }
}

extern "C" void kernel_launch(void* const* d_in, const int* in_sizes, int n_in,
                              void* d_out, int out_size, void* d_ws, size_t ws_size,
                              hipStream_t stream)
{
    const float* nodes = (const float*)d_in[0];
    const int*   edges = (const int*)d_in[1];
    const float* ew    = (const float*)d_in[2];
    const float *W1 = (const float*)d_in[3],  *b1 = (const float*)d_in[4],
                *g1 = (const float*)d_in[5],  *be1 = (const float*)d_in[6];
    const float *W2 = (const float*)d_in[7],  *b2 = (const float*)d_in[8],
                *g2 = (const float*)d_in[9],  *be2 = (const float*)d_in[10];
    const float *W3 = (const float*)d_in[11], *b3 = (const float*)d_in[12],
                *g3 = (const float*)d_in[13], *be3 = (const float*)d_in[14];
    const float *W4 = (const float*)d_in[15], *b4 = (const float*)d_in[16],
                *g4 = (const float*)d_in[17], *be4 = (const float*)d_in[18];

    const int N = in_sizes[0] / DIM;     // 100000
    const int E = in_sizes[2];           // 3200000

    // workspace layout (CSR path):
    //   agg_in  : N*DIM f32
    //   agg_out : N*DIM f32
    //   deg     : 2N u32
    //   off     : 2N u32
    //   cur     : 2N u32
    //   bsum    : nb1 u32 (padded)
    //   lists   : 2E uint2
    const size_t aggB   = (size_t)2 * N * DIM * sizeof(float);
    const size_t degB   = (size_t)2 * N * sizeof(u32);
    const int    total  = 2 * N;
    const int    nb1    = (total + 255) / 256;
    const size_t bsumB  = ((size_t)nb1 * sizeof(u32) + 255) & ~(size_t)255;
    const size_t listsB = (size_t)2 * E * sizeof(uint2);
    const size_t need   = aggB + 3 * degB + bsumB + listsB;

    float* agg_in  = (float*)d_ws;
    float* agg_out = agg_in + (size_t)N * DIM;

    if (ws_size >= need) {
        char* p = (char*)d_ws + aggB;
        u32* deg  = (u32*)p;            p += degB;
        u32* off  = (u32*)p;            p += degB;
        u32* cur  = (u32*)p;            p += degB;
        u32* bsum = (u32*)p;            p += bsumB;
        uint2* lists = (uint2*)p;

        hipMemsetAsync(deg, 0, degB, stream);

        int egrid = (E + 255) / 256;
        hist_kernel<<<egrid, 256, 0, stream>>>(edges, deg, E, N);
        scan_block_sums<<<nb1, 256, 0, stream>>>(deg, bsum, total);
        scan_carry<<<1, 1024, 0, stream>>>(bsum, nb1);
        scan_final<<<nb1, 256, 0, stream>>>(deg, bsum, off, cur, total);
        fill_kernel<<<egrid, 256, 0, stream>>>(edges, ew, cur, lists, E, N);
        int ggrid = (N * 16 + 255) / 256;
        gather_kernel<<<ggrid, 256, 0, stream>>>(nodes, lists, off, deg,
                                                 agg_in, agg_out, N);
    } else {
        // fallback: verified round-0 atomic scatter
        hipMemsetAsync(d_ws, 0, aggB, stream);
        long long ethreads = (long long)E * 16;
        int egrid = (int)((ethreads + 255) / 256);
        edge_scatter_fallback<<<egrid, 256, 0, stream>>>(nodes, edges, ew,
                                                         agg_in, agg_out, E);
    }

    int mgrid = (N + TN - 1) / TN;
    mlp_kernel<<<mgrid, 256, 0, stream>>>(agg_in, agg_out, nodes,
        W1, b1, g1, be1, W2, b2, g2, be2, W3, b3, g3, be3, W4, b4, g4, be4,
        (float*)d_out, N);
}

// Round 3
// 1050.119 us; speedup vs baseline: 1.1114x; 1.1114x over previous
//
#include <hip/hip_runtime.h>
#include <stdint.h>

#define DIM 16
#define HID 128
#define TN  64            // nodes per block (MLP)
#define ROWF 132          // LDS row stride in floats (128 + 4 pad)
#define EPSF 1e-5f

#define BN   256          // nodes per bucket (agg tile = 256*16 f32 = 16 KB LDS)
#define EPB  4096         // edges per binning block

typedef unsigned int u32;

// NaN-free tanh; |x| <= ~12 here (LN output bounded by sqrt(H))
__device__ __forceinline__ float safe_tanh(float x) {
    float a = fabsf(x);
    float e = __expf(2.0f * a);
    float t = 1.0f - 2.0f / (e + 1.0f);
    return copysignf(t, x);
}

// ---------------- binned aggregation path ---------------------------------
// bucket of node n = n>>8. Bucket-direction index: in = (dst>>8),
// out = NB + (src>>8). Record: x = neighbor(17b) | local(8b)<<17, y = w bits.

__global__ void __launch_bounds__(256) ghist_kernel(
    const int* __restrict__ edges, u32* __restrict__ ghist, int E, int NB)
{
    __shared__ u32 h[2048];
    const int tid = threadIdx.x;
    const int tot = 2 * NB;
    for (int i = tid; i < tot; i += 256) h[i] = 0;
    __syncthreads();
    const int base = blockIdx.x * EPB;
    for (int i = tid; i < EPB; i += 256) {
        int e = base + i;
        if (e < E) {
            int src = edges[2 * e];
            int dst = edges[2 * e + 1];
            atomicAdd(&h[dst >> 8], 1u);
            atomicAdd(&h[NB + (src >> 8)], 1u);
        }
    }
    __syncthreads();
    for (int i = tid; i < tot; i += 256) {
        u32 c = h[i];
        if (c) atomicAdd(&ghist[i], c);
    }
}

// single-block exclusive scan: off[0..tot] (incl. total), gcur = copy
__global__ void __launch_bounds__(1024) scan_offsets(
    const u32* __restrict__ ghist, u32* __restrict__ off,
    u32* __restrict__ gcur, int tot)
{
    __shared__ u32 sm[1024];
    const int tid = threadIdx.x;
    u32 carry = 0;
    for (int b0 = 0; b0 < tot; b0 += 1024) {
        int i = b0 + tid;
        u32 v = (i < tot) ? ghist[i] : 0u;
        __syncthreads();
        sm[tid] = v;
        __syncthreads();
        for (int s = 1; s < 1024; s <<= 1) {
            u32 t = (tid >= s) ? sm[tid - s] : 0u;
            __syncthreads();
            sm[tid] += t;
            __syncthreads();
        }
        u32 excl = sm[tid] - v + carry;
        if (i < tot) { off[i] = excl; gcur[i] = excl; }
        carry += sm[1023];
    }
    if (tid == 0) off[tot] = carry;
}

// bin edges into bucket runs: one global cursor atomic per (block,bucket),
// records land in contiguous ~84B runs -> line-efficient writeback.
__global__ void __launch_bounds__(256) bin_kernel(
    const int* __restrict__ edges, const float* __restrict__ ew,
    u32* __restrict__ gcur, uint2* __restrict__ lists, int E, int NB)
{
    __shared__ u32 hcnt[2048];
    __shared__ u32 hbase[2048];
    const int tid = threadIdx.x;
    const int tot = 2 * NB;
    for (int i = tid; i < tot; i += 256) hcnt[i] = 0;
    __syncthreads();
    const int base = blockIdx.x * EPB;
    for (int i = tid; i < EPB; i += 256) {
        int e = base + i;
        if (e < E) {
            int src = edges[2 * e];
            int dst = edges[2 * e + 1];
            atomicAdd(&hcnt[dst >> 8], 1u);
            atomicAdd(&hcnt[NB + (src >> 8)], 1u);
        }
    }
    __syncthreads();
    for (int i = tid; i < tot; i += 256) {
        u32 c = hcnt[i];
        hbase[i] = c ? atomicAdd(&gcur[i], c) : 0u;
        hcnt[i] = 0;        // safe: all counting atomics done (barrier above)
    }
    __syncthreads();
    for (int i = tid; i < EPB; i += 256) {
        int e = base + i;
        if (e < E) {
            int src = edges[2 * e];
            int dst = edges[2 * e + 1];
            u32 wb = __float_as_uint(ew[e]);
            int b1 = dst >> 8;
            u32 r1 = atomicAdd(&hcnt[b1], 1u);
            lists[hbase[b1] + r1] =
                make_uint2((u32)src | ((u32)(dst & 255) << 17), wb);
            int b2 = NB + (src >> 8);
            u32 r2 = atomicAdd(&hcnt[b2], 1u);
            lists[hbase[b2] + r2] =
                make_uint2((u32)dst | ((u32)(src & 255) << 17), wb);
        }
    }
}

// one block per bucket-direction: LDS-atomic accumulate, coalesced writeout
__global__ void __launch_bounds__(256) bucket_agg_kernel(
    const float* __restrict__ nodes, const uint2* __restrict__ lists,
    const u32* __restrict__ off, float* __restrict__ agg_in,
    float* __restrict__ agg_out, int N, int NB)
{
    __shared__ float sagg[BN * DIM];   // 16 KB
    const int tid = threadIdx.x;
    const int bd = blockIdx.x;         // 0..2NB-1
    for (int i = tid; i < BN * DIM; i += 256) sagg[i] = 0.f;
    __syncthreads();

    const u32 s = off[bd], epos = off[bd + 1];
    const int c = tid & 15;
    // 16 lanes per record; 2 independent records per thread per iteration
    u32 r = s + (tid >> 4);
    for (; r + 16 < epos; r += 32) {
        uint2 e0 = lists[r];
        uint2 e1 = lists[r + 16];
        float v0 = nodes[(e0.x & 0x1FFFF) * DIM + c] * __uint_as_float(e0.y);
        float v1 = nodes[(e1.x & 0x1FFFF) * DIM + c] * __uint_as_float(e1.y);
        atomicAdd(&sagg[((e0.x >> 17) & 255) * DIM + c], v0);
        atomicAdd(&sagg[((e1.x >> 17) & 255) * DIM + c], v1);
    }
    if (r < epos) {
        uint2 e0 = lists[r];
        float v0 = nodes[(e0.x & 0x1FFFF) * DIM + c] * __uint_as_float(e0.y);
        atomicAdd(&sagg[((e0.x >> 17) & 255) * DIM + c], v0);
    }
    __syncthreads();

    const int bucket = (bd < NB) ? bd : bd - NB;
    float* dst = (bd < NB) ? agg_in : agg_out;
    const int nb0 = bucket * BN;
    for (int i = tid; i < BN * DIM / 4; i += 256) {
        int idx = i * 4;
        int node = nb0 + (idx >> 4);
        if (node < N)
            *(float4*)&dst[(size_t)node * DIM + (idx & 15)] =
                *(float4*)&sagg[idx];
    }
}

// ---------------- fallback: fp32 atomic scatter (round-0, verified) -------
__global__ void __launch_bounds__(256) edge_scatter_fallback(
    const float* __restrict__ nodes, const int* __restrict__ edges,
    const float* __restrict__ ew, float* __restrict__ agg_in,
    float* __restrict__ agg_out, int nEdges)
{
    int gid = blockIdx.x * 256 + threadIdx.x;
    int e = gid >> 4;
    if (e >= nEdges) return;
    int c = gid & 15;
    int src = edges[2 * e];
    int dst = edges[2 * e + 1];
    float w  = ew[e];
    float vs = nodes[src * DIM + c];
    float vd = nodes[dst * DIM + c];
    atomicAdd(&agg_in[dst * DIM + c], vs * w);
    atomicAdd(&agg_out[src * DIM + c], vd * w);
}

// ---------------- Phase 2: fused 4-layer MLP (round-0, verified) ----------
template<int K>
__device__ __forceinline__ void dense_ln_tanh(
    const float* __restrict__ W, const float* __restrict__ bias,
    const float* __restrict__ g, const float* __restrict__ be,
    float (&X)[TN][ROWF], int tid)
{
    const int c0 = (tid & 31) * 4;   // column group: lanes 0..31 cover 128 cols
    const int n0 = (tid >> 5) * 8;   // row group: 8 rows per thread
    float acc[8][4];
    {
        float4 bv = *(const float4*)(bias + c0);
        #pragma unroll
        for (int i = 0; i < 8; ++i) {
            acc[i][0] = bv.x; acc[i][1] = bv.y; acc[i][2] = bv.z; acc[i][3] = bv.w;
        }
    }

    #pragma unroll 2
    for (int k = 0; k < K; k += 4) {
        float xr[8][4];
        #pragma unroll
        for (int i = 0; i < 8; ++i) {
            float4 t = *(const float4*)&X[n0 + i][k];
            xr[i][0] = t.x; xr[i][1] = t.y; xr[i][2] = t.z; xr[i][3] = t.w;
        }
        float w[4][4];
        #pragma unroll
        for (int kk = 0; kk < 4; ++kk) {
            float4 t = *(const float4*)(W + (k + kk) * HID + c0);
            w[kk][0] = t.x; w[kk][1] = t.y; w[kk][2] = t.z; w[kk][3] = t.w;
        }
        #pragma unroll
        for (int kk = 0; kk < 4; ++kk)
            #pragma unroll
            for (int i = 0; i < 8; ++i)
                #pragma unroll
                for (int j = 0; j < 4; ++j) acc[i][j] += xr[i][kk] * w[kk][j];
    }

    float s[8], q[8];
    #pragma unroll
    for (int i = 0; i < 8; ++i) {
        s[i] = acc[i][0] + acc[i][1] + acc[i][2] + acc[i][3];
        q[i] = acc[i][0]*acc[i][0] + acc[i][1]*acc[i][1]
             + acc[i][2]*acc[i][2] + acc[i][3]*acc[i][3];
    }
    #pragma unroll
    for (int m = 1; m <= 16; m <<= 1) {
        #pragma unroll
        for (int i = 0; i < 8; ++i) {
            s[i] += __shfl_xor(s[i], m);
            q[i] += __shfl_xor(q[i], m);
        }
    }

    float4 gv  = *(const float4*)(g + c0);
    float4 bev = *(const float4*)(be + c0);
    float gr[4]  = {gv.x, gv.y, gv.z, gv.w};
    float ber[4] = {bev.x, bev.y, bev.z, bev.w};

    __syncthreads();   // all X reads of this layer complete before overwrite
    #pragma unroll
    for (int i = 0; i < 8; ++i) {
        float mean = s[i] * (1.0f / HID);
        float var  = fmaxf(q[i] * (1.0f / HID) - mean * mean, 0.0f);
        float r = rsqrtf(var + EPSF);
        float o[4];
        #pragma unroll
        for (int j = 0; j < 4; ++j)
            o[j] = safe_tanh((acc[i][j] - mean) * r * gr[j] + ber[j]);
        *(float4*)&X[n0 + i][c0] = make_float4(o[0], o[1], o[2], o[3]);
    }
    __syncthreads();
}

__global__ void __launch_bounds__(256, 3) mlp_kernel(
    const float* __restrict__ agg_in, const float* __restrict__ agg_out,
    const float* __restrict__ nodes,
    const float* __restrict__ W1, const float* __restrict__ b1, const float* __restrict__ g1, const float* __restrict__ be1,
    const float* __restrict__ W2, const float* __restrict__ b2, const float* __restrict__ g2, const float* __restrict__ be2,
    const float* __restrict__ W3, const float* __restrict__ b3, const float* __restrict__ g3, const float* __restrict__ be3,
    const float* __restrict__ W4, const float* __restrict__ b4, const float* __restrict__ g4, const float* __restrict__ be4,
    float* __restrict__ out, int nNodes)
{
    __shared__ float X[TN][ROWF];

    const int tid = threadIdx.x;
    const int node0 = blockIdx.x * TN;

    // stage x = concat(agg_in, agg_out, nodes): 64 rows x 12 float4
    for (int i = tid; i < TN * 12; i += 256) {
        int n = i / 12, c4 = i - n * 12;
        int gn = node0 + n;
        float4 v = make_float4(0.f, 0.f, 0.f, 0.f);
        if (gn < nNodes) {
            if (c4 < 4)      v = *(const float4*)(agg_in  + (size_t)gn * DIM + c4 * 4);
            else if (c4 < 8) v = *(const float4*)(agg_out + (size_t)gn * DIM + (c4 - 4) * 4);
            else             v = *(const float4*)(nodes   + (size_t)gn * DIM + (c4 - 8) * 4);
        }
        *(float4*)&X[n][c4 * 4] = v;
    }
    __syncthreads();

    dense_ln_tanh<48>(W1, b1, g1, be1, X, tid);
    dense_ln_tanh<128>(W2, b2, g2, be2, X, tid);
    dense_ln_tanh<128>(W3, b3, g3, be3, X, tid);

    // Layer 4: 128 -> 16, LN over 16, tanh, store fp32
    {
        const int c2 = tid & 15;
        const int nb = tid >> 4;   // 0..15; handles nodes nb + {0,16,32,48}
        float a[4];
        {
            float bv = b4[c2];
            #pragma unroll
            for (int t = 0; t < 4; ++t) a[t] = bv;
        }
        #pragma unroll 2
        for (int k = 0; k < HID; k += 4) {
            float w[4];
            #pragma unroll
            for (int kk = 0; kk < 4; ++kk) w[kk] = W4[(k + kk) * DIM + c2];
            #pragma unroll
            for (int t = 0; t < 4; ++t) {
                float4 x = *(const float4*)&X[nb + 16 * t][k];
                a[t] += x.x * w[0] + x.y * w[1] + x.z * w[2] + x.w * w[3];
            }
        }
        float s[4], q[4];
        #pragma unroll
        for (int t = 0; t < 4; ++t) { s[t] = a[t]; q[t] = a[t] * a[t]; }
        #pragma unroll
        for (int m = 1; m <= 8; m <<= 1) {
            #pragma unroll
            for (int t = 0; t < 4; ++t) {
                s[t] += __shfl_xor(s[t], m);
                q[t] += __shfl_xor(q[t], m);
            }
        }
        float g4v = g4[c2], be4v = be4[c2];
        #pragma unroll
        for (int t = 0; t < 4; ++t) {
            int node = node0 + nb + 16 * t;
            if (node < nNodes) {
                float mean = s[t] * (1.0f / DIM);
                float var  = fmaxf(q[t] * (1.0f / DIM) - mean * mean, 0.0f);
                float o = safe_tanh((a[t] - mean) * rsqrtf(var + EPSF) * g4v + be4v);
                out[(size_t)node * DIM + c2] = o;
            }
        }
    }
}

extern "C" void kernel_launch(void* const* d_in, const int* in_sizes, int n_in,
                              void* d_out, int out_size, void* d_ws, size_t ws_size,
                              hipStream_t stream)
{
    const float* nodes = (const float*)d_in[0];
    const int*   edges = (const int*)d_in[1];
    const float* ew    = (const float*)d_in[2];
    const float *W1 = (const float*)d_in[3],  *b1 = (const float*)d_in[4],
                *g1 = (const float*)d_in[5],  *be1 = (const float*)d_in[6];
    const float *W2 = (const float*)d_in[7],  *b2 = (const float*)d_in[8],
                *g2 = (const float*)d_in[9],  *be2 = (const float*)d_in[10];
    const float *W3 = (const float*)d_in[11], *b3 = (const float*)d_in[12],
                *g3 = (const float*)d_in[13], *be3 = (const float*)d_in[14];
    const float *W4 = (const float*)d_in[15], *b4 = (const float*)d_in[16],
                *g4 = (const float*)d_in[17], *be4 = (const float*)d_in[18];

    const int N = in_sizes[0] / DIM;     // 100000
    const int E = in_sizes[2];           // 3200000

    const int NB  = (N + BN - 1) / BN;   // 391
    const int tot = 2 * NB;

    // workspace layout:
    //   agg_in/agg_out : 2*N*DIM f32
    //   ghist (tot) | off (tot+1) | gcur (tot)  u32, padded to 256B
    //   lists : 2E uint2
    const size_t aggB   = (size_t)2 * N * DIM * sizeof(float);
    const size_t metaB  = (((size_t)(3 * tot + 1) * sizeof(u32)) + 255) & ~(size_t)255;
    const size_t listsB = (size_t)2 * E * sizeof(uint2);
    const size_t need   = aggB + metaB + listsB;

    float* agg_in  = (float*)d_ws;
    float* agg_out = agg_in + (size_t)N * DIM;

    if (ws_size >= need && tot <= 2048) {
        char* p = (char*)d_ws + aggB;
        u32* ghist = (u32*)p;
        u32* off   = ghist + tot;
        u32* gcur  = off + tot + 1;
        uint2* lists = (uint2*)((char*)d_ws + aggB + metaB);

        hipMemsetAsync(ghist, 0, (size_t)tot * sizeof(u32), stream);

        const int gB = (E + EPB - 1) / EPB;
        ghist_kernel<<<gB, 256, 0, stream>>>(edges, ghist, E, NB);
        scan_offsets<<<1, 1024, 0, stream>>>(ghist, off, gcur, tot);
        bin_kernel<<<gB, 256, 0, stream>>>(edges, ew, gcur, lists, E, NB);
        bucket_agg_kernel<<<tot, 256, 0, stream>>>(nodes, lists, off,
                                                   agg_in, agg_out, N, NB);
    } else {
        // fallback: verified round-0 atomic scatter
        hipMemsetAsync(d_ws, 0, aggB, stream);
        long long ethreads = (long long)E * 16;
        int egrid = (int)((ethreads + 255) / 256);
        edge_scatter_fallback<<<egrid, 256, 0, stream>>>(nodes, edges, ew,
                                                         agg_in, agg_out, E);
    }

    int mgrid = (N + TN - 1) / TN;
    mlp_kernel<<<mgrid, 256, 0, stream>>>(agg_in, agg_out, nodes,
        W1, b1, g1, be1, W2, b2, g2, be2, W3, b3, g3, be3, W4, b4, g4, be4,
        (float*)d_out, N);
}

// Round 4
// 962.964 us; speedup vs baseline: 1.2120x; 1.0905x over previous
//
#include <hip/hip_runtime.h>
#include <stdint.h>

#define DIM 16
#define HID 128
#define TN  64            // nodes per block (MLP)
#define ROWF 132          // LDS row stride in floats (128 + 4 pad)
#define EPSF 1e-5f

#define BN   256          // nodes per bucket
#define EPB  4096         // edges per binning block
#define QSPLIT 4          // agg blocks per bucket-direction
#define QN   (BN / QSPLIT) // 64 nodes per agg sub-tile (4 KB LDS)

typedef unsigned int u32;

// NaN-free tanh; |x| <= ~12 here (LN output bounded by sqrt(H))
__device__ __forceinline__ float safe_tanh(float x) {
    float a = fabsf(x);
    float e = __expf(2.0f * a);
    float t = 1.0f - 2.0f / (e + 1.0f);
    return copysignf(t, x);
}

// ---------------- binned aggregation path ---------------------------------
// bucket of node n = n>>8. Bucket-direction index: in = (dst>>8),
// out = NB + (src>>8). Record: x = neighbor(17b) | local(8b)<<17, y = w bits.

__global__ void __launch_bounds__(256) ghist_kernel(
    const int* __restrict__ edges, u32* __restrict__ ghist, int E, int NB)
{
    __shared__ u32 h[2048];
    const int tid = threadIdx.x;
    const int tot = 2 * NB;
    for (int i = tid; i < tot; i += 256) h[i] = 0;
    __syncthreads();
    const int base = blockIdx.x * EPB;
    for (int i = tid; i < EPB; i += 256) {
        int e = base + i;
        if (e < E) {
            int src = edges[2 * e];
            int dst = edges[2 * e + 1];
            atomicAdd(&h[dst >> 8], 1u);
            atomicAdd(&h[NB + (src >> 8)], 1u);
        }
    }
    __syncthreads();
    for (int i = tid; i < tot; i += 256) {
        u32 c = h[i];
        if (c) atomicAdd(&ghist[i], c);
    }
}

// single-block exclusive scan: off[0..tot] (incl. total), gcur = copy
__global__ void __launch_bounds__(1024) scan_offsets(
    const u32* __restrict__ ghist, u32* __restrict__ off,
    u32* __restrict__ gcur, int tot)
{
    __shared__ u32 sm[1024];
    const int tid = threadIdx.x;
    u32 carry = 0;
    for (int b0 = 0; b0 < tot; b0 += 1024) {
        int i = b0 + tid;
        u32 v = (i < tot) ? ghist[i] : 0u;
        __syncthreads();
        sm[tid] = v;
        __syncthreads();
        for (int s = 1; s < 1024; s <<= 1) {
            u32 t = (tid >= s) ? sm[tid - s] : 0u;
            __syncthreads();
            sm[tid] += t;
            __syncthreads();
        }
        u32 excl = sm[tid] - v + carry;
        if (i < tot) { off[i] = excl; gcur[i] = excl; }
        carry += sm[1023];
    }
    if (tid == 0) off[tot] = carry;
}

// bin edges into bucket runs: one global cursor atomic per (block,bucket),
// records land in contiguous ~84B runs -> line-efficient writeback.
__global__ void __launch_bounds__(256) bin_kernel(
    const int* __restrict__ edges, const float* __restrict__ ew,
    u32* __restrict__ gcur, uint2* __restrict__ lists, int E, int NB)
{
    __shared__ u32 hcnt[2048];
    __shared__ u32 hbase[2048];
    const int tid = threadIdx.x;
    const int tot = 2 * NB;
    for (int i = tid; i < tot; i += 256) hcnt[i] = 0;
    __syncthreads();
    const int base = blockIdx.x * EPB;
    for (int i = tid; i < EPB; i += 256) {
        int e = base + i;
        if (e < E) {
            int src = edges[2 * e];
            int dst = edges[2 * e + 1];
            atomicAdd(&hcnt[dst >> 8], 1u);
            atomicAdd(&hcnt[NB + (src >> 8)], 1u);
        }
    }
    __syncthreads();
    for (int i = tid; i < tot; i += 256) {
        u32 c = hcnt[i];
        hbase[i] = c ? atomicAdd(&gcur[i], c) : 0u;
        hcnt[i] = 0;        // safe: all counting atomics done (barrier above)
    }
    __syncthreads();
    for (int i = tid; i < EPB; i += 256) {
        int e = base + i;
        if (e < E) {
            int src = edges[2 * e];
            int dst = edges[2 * e + 1];
            u32 wb = __float_as_uint(ew[e]);
            int b1 = dst >> 8;
            u32 r1 = atomicAdd(&hcnt[b1], 1u);
            lists[hbase[b1] + r1] =
                make_uint2((u32)src | ((u32)(dst & 255) << 17), wb);
            int b2 = NB + (src >> 8);
            u32 r2 = atomicAdd(&hcnt[b2], 1u);
            lists[hbase[b2] + r2] =
                make_uint2((u32)dst | ((u32)(src & 255) << 17), wb);
        }
    }
}

// QSPLIT blocks per bucket-direction: block (bd,q) scans bd's records and
// gathers only local rows in its 64-node quarter -> 4 KB LDS tile.
// 16 lanes per record (lane = component); filter is group-uniform and
// decided BEFORE the gather, so skipped records cost only the 8 B scan.
__global__ void __launch_bounds__(256) bucket_agg_kernel(
    const float* __restrict__ nodes, const uint2* __restrict__ lists,
    const u32* __restrict__ off, float* __restrict__ agg_in,
    float* __restrict__ agg_out, int N, int NB)
{
    __shared__ float sagg[QN * DIM];   // 4 KB
    const int tid = threadIdx.x;
    const int bd = blockIdx.x >> 2;    // bucket-direction 0..2NB-1
    const u32 q  = blockIdx.x & 3;     // quarter 0..3
    for (int i = tid; i < QN * DIM; i += 256) sagg[i] = 0.f;
    __syncthreads();

    const u32 s = off[bd], epos = off[bd + 1];
    const int c = tid & 15;

    u32 r = s + (tid >> 4);
    // 4-record ILP: independent scan loads issue together
    for (; r + 48 < epos; r += 64) {
        uint2 e0 = lists[r];
        uint2 e1 = lists[r + 16];
        uint2 e2 = lists[r + 32];
        uint2 e3 = lists[r + 48];
        u32 l0 = (e0.x >> 17) & 255, l1 = (e1.x >> 17) & 255;
        u32 l2 = (e2.x >> 17) & 255, l3 = (e3.x >> 17) & 255;
        if ((l0 >> 6) == q) {
            float v = nodes[(e0.x & 0x1FFFF) * DIM + c] * __uint_as_float(e0.y);
            atomicAdd(&sagg[(l0 & 63) * DIM + c], v);
        }
        if ((l1 >> 6) == q) {
            float v = nodes[(e1.x & 0x1FFFF) * DIM + c] * __uint_as_float(e1.y);
            atomicAdd(&sagg[(l1 & 63) * DIM + c], v);
        }
        if ((l2 >> 6) == q) {
            float v = nodes[(e2.x & 0x1FFFF) * DIM + c] * __uint_as_float(e2.y);
            atomicAdd(&sagg[(l2 & 63) * DIM + c], v);
        }
        if ((l3 >> 6) == q) {
            float v = nodes[(e3.x & 0x1FFFF) * DIM + c] * __uint_as_float(e3.y);
            atomicAdd(&sagg[(l3 & 63) * DIM + c], v);
        }
    }
    for (; r < epos; r += 16) {
        uint2 e0 = lists[r];
        u32 l0 = (e0.x >> 17) & 255;
        if ((l0 >> 6) == q) {
            float v = nodes[(e0.x & 0x1FFFF) * DIM + c] * __uint_as_float(e0.y);
            atomicAdd(&sagg[(l0 & 63) * DIM + c], v);
        }
    }
    __syncthreads();

    const int bucket = (bd < NB) ? bd : bd - NB;
    float* dst = (bd < NB) ? agg_in : agg_out;
    const int nb0 = bucket * BN + (int)q * QN;
    // 64 rows x 16 f32 = 256 float4: exactly one per thread
    {
        int idx = tid * 4;
        int node = nb0 + (idx >> 4);
        if (node < N)
            *(float4*)&dst[(size_t)node * DIM + (idx & 15)] =
                *(float4*)&sagg[idx];
    }
}

// ---------------- fallback: fp32 atomic scatter (round-0, verified) -------
__global__ void __launch_bounds__(256) edge_scatter_fallback(
    const float* __restrict__ nodes, const int* __restrict__ edges,
    const float* __restrict__ ew, float* __restrict__ agg_in,
    float* __restrict__ agg_out, int nEdges)
{
    int gid = blockIdx.x * 256 + threadIdx.x;
    int e = gid >> 4;
    if (e >= nEdges) return;
    int c = gid & 15;
    int src = edges[2 * e];
    int dst = edges[2 * e + 1];
    float w  = ew[e];
    float vs = nodes[src * DIM + c];
    float vd = nodes[dst * DIM + c];
    atomicAdd(&agg_in[dst * DIM + c], vs * w);
    atomicAdd(&agg_out[src * DIM + c], vd * w);
}

// ---------------- Phase 2: fused 4-layer MLP (round-0, verified) ----------
template<int K>
__device__ __forceinline__ void dense_ln_tanh(
    const float* __restrict__ W, const float* __restrict__ bias,
    const float* __restrict__ g, const float* __restrict__ be,
    float (&X)[TN][ROWF], int tid)
{
    const int c0 = (tid & 31) * 4;   // column group: lanes 0..31 cover 128 cols
    const int n0 = (tid >> 5) * 8;   // row group: 8 rows per thread
    float acc[8][4];
    {
        float4 bv = *(const float4*)(bias + c0);
        #pragma unroll
        for (int i = 0; i < 8; ++i) {
            acc[i][0] = bv.x; acc[i][1] = bv.y; acc[i][2] = bv.z; acc[i][3] = bv.w;
        }
    }

    #pragma unroll 2
    for (int k = 0; k < K; k += 4) {
        float xr[8][4];
        #pragma unroll
        for (int i = 0; i < 8; ++i) {
            float4 t = *(const float4*)&X[n0 + i][k];
            xr[i][0] = t.x; xr[i][1] = t.y; xr[i][2] = t.z; xr[i][3] = t.w;
        }
        float w[4][4];
        #pragma unroll
        for (int kk = 0; kk < 4; ++kk) {
            float4 t = *(const float4*)(W + (k + kk) * HID + c0);
            w[kk][0] = t.x; w[kk][1] = t.y; w[kk][2] = t.z; w[kk][3] = t.w;
        }
        #pragma unroll
        for (int kk = 0; kk < 4; ++kk)
            #pragma unroll
            for (int i = 0; i < 8; ++i)
                #pragma unroll
                for (int j = 0; j < 4; ++j) acc[i][j] += xr[i][kk] * w[kk][j];
    }

    float s[8], q[8];
    #pragma unroll
    for (int i = 0; i < 8; ++i) {
        s[i] = acc[i][0] + acc[i][1] + acc[i][2] + acc[i][3];
        q[i] = acc[i][0]*acc[i][0] + acc[i][1]*acc[i][1]
             + acc[i][2]*acc[i][2] + acc[i][3]*acc[i][3];
    }
    #pragma unroll
    for (int m = 1; m <= 16; m <<= 1) {
        #pragma unroll
        for (int i = 0; i < 8; ++i) {
            s[i] += __shfl_xor(s[i], m);
            q[i] += __shfl_xor(q[i], m);
        }
    }

    float4 gv  = *(const float4*)(g + c0);
    float4 bev = *(const float4*)(be + c0);
    float gr[4]  = {gv.x, gv.y, gv.z, gv.w};
    float ber[4] = {bev.x, bev.y, bev.z, bev.w};

    __syncthreads();   // all X reads of this layer complete before overwrite
    #pragma unroll
    for (int i = 0; i < 8; ++i) {
        float mean = s[i] * (1.0f / HID);
        float var  = fmaxf(q[i] * (1.0f / HID) - mean * mean, 0.0f);
        float r = rsqrtf(var + EPSF);
        float o[4];
        #pragma unroll
        for (int j = 0; j < 4; ++j)
            o[j] = safe_tanh((acc[i][j] - mean) * r * gr[j] + ber[j]);
        *(float4*)&X[n0 + i][c0] = make_float4(o[0], o[1], o[2], o[3]);
    }
    __syncthreads();
}

__global__ void __launch_bounds__(256, 3) mlp_kernel(
    const float* __restrict__ agg_in, const float* __restrict__ agg_out,
    const float* __restrict__ nodes,
    const float* __restrict__ W1, const float* __restrict__ b1, const float* __restrict__ g1, const float* __restrict__ be1,
    const float* __restrict__ W2, const float* __restrict__ b2, const float* __restrict__ g2, const float* __restrict__ be2,
    const float* __restrict__ W3, const float* __restrict__ b3, const float* __restrict__ g3, const float* __restrict__ be3,
    const float* __restrict__ W4, const float* __restrict__ b4, const float* __restrict__ g4, const float* __restrict__ be4,
    float* __restrict__ out, int nNodes)
{
    __shared__ float X[TN][ROWF];

    const int tid = threadIdx.x;
    const int node0 = blockIdx.x * TN;

    // stage x = concat(agg_in, agg_out, nodes): 64 rows x 12 float4
    for (int i = tid; i < TN * 12; i += 256) {
        int n = i / 12, c4 = i - n * 12;
        int gn = node0 + n;
        float4 v = make_float4(0.f, 0.f, 0.f, 0.f);
        if (gn < nNodes) {
            if (c4 < 4)      v = *(const float4*)(agg_in  + (size_t)gn * DIM + c4 * 4);
            else if (c4 < 8) v = *(const float4*)(agg_out + (size_t)gn * DIM + (c4 - 4) * 4);
            else             v = *(const float4*)(nodes   + (size_t)gn * DIM + (c4 - 8) * 4);
        }
        *(float4*)&X[n][c4 * 4] = v;
    }
    __syncthreads();

    dense_ln_tanh<48>(W1, b1, g1, be1, X, tid);
    dense_ln_tanh<128>(W2, b2, g2, be2, X, tid);
    dense_ln_tanh<128>(W3, b3, g3, be3, X, tid);

    // Layer 4: 128 -> 16, LN over 16, tanh, store fp32
    {
        const int c2 = tid & 15;
        const int nb = tid >> 4;   // 0..15; handles nodes nb + {0,16,32,48}
        float a[4];
        {
            float bv = b4[c2];
            #pragma unroll
            for (int t = 0; t < 4; ++t) a[t] = bv;
        }
        #pragma unroll 2
        for (int k = 0; k < HID; k += 4) {
            float w[4];
            #pragma unroll
            for (int kk = 0; kk < 4; ++kk) w[kk] = W4[(k + kk) * DIM + c2];
            #pragma unroll
            for (int t = 0; t < 4; ++t) {
                float4 x = *(const float4*)&X[nb + 16 * t][k];
                a[t] += x.x * w[0] + x.y * w[1] + x.z * w[2] + x.w * w[3];
            }
        }
        float s[4], q[4];
        #pragma unroll
        for (int t = 0; t < 4; ++t) { s[t] = a[t]; q[t] = a[t] * a[t]; }
        #pragma unroll
        for (int m = 1; m <= 8; m <<= 1) {
            #pragma unroll
            for (int t = 0; t < 4; ++t) {
                s[t] += __shfl_xor(s[t], m);
                q[t] += __shfl_xor(q[t], m);
            }
        }
        float g4v = g4[c2], be4v = be4[c2];
        #pragma unroll
        for (int t = 0; t < 4; ++t) {
            int node = node0 + nb + 16 * t;
            if (node < nNodes) {
                float mean = s[t] * (1.0f / DIM);
                float var  = fmaxf(q[t] * (1.0f / DIM) - mean * mean, 0.0f);
                float o = safe_tanh((a[t] - mean) * rsqrtf(var + EPSF) * g4v + be4v);
                out[(size_t)node * DIM + c2] = o;
            }
        }
    }
}

extern "C" void kernel_launch(void* const* d_in, const int* in_sizes, int n_in,
                              void* d_out, int out_size, void* d_ws, size_t ws_size,
                              hipStream_t stream)
{
    const float* nodes = (const float*)d_in[0];
    const int*   edges = (const int*)d_in[1];
    const float* ew    = (const float*)d_in[2];
    const float *W1 = (const float*)d_in[3],  *b1 = (const float*)d_in[4],
                *g1 = (const float*)d_in[5],  *be1 = (const float*)d_in[6];
    const float *W2 = (const float*)d_in[7],  *b2 = (const float*)d_in[8],
                *g2 = (const float*)d_in[9],  *be2 = (const float*)d_in[10];
    const float *W3 = (const float*)d_in[11], *b3 = (const float*)d_in[12],
                *g3 = (const float*)d_in[13], *be3 = (const float*)d_in[14];
    const float *W4 = (const float*)d_in[15], *b4 = (const float*)d_in[16],
                *g4 = (const float*)d_in[17], *be4 = (const float*)d_in[18];

    const int N = in_sizes[0] / DIM;     // 100000
    const int E = in_sizes[2];           // 3200000

    const int NB  = (N + BN - 1) / BN;   // 391
    const int tot = 2 * NB;

    // workspace layout:
    //   agg_in/agg_out : 2*N*DIM f32
    //   ghist (tot) | off (tot+1) | gcur (tot)  u32, padded to 256B
    //   lists : 2E uint2
    const size_t aggB   = (size_t)2 * N * DIM * sizeof(float);
    const size_t metaB  = (((size_t)(3 * tot + 1) * sizeof(u32)) + 255) & ~(size_t)255;
    const size_t listsB = (size_t)2 * E * sizeof(uint2);
    const size_t need   = aggB + metaB + listsB;

    float* agg_in  = (float*)d_ws;
    float* agg_out = agg_in + (size_t)N * DIM;

    if (ws_size >= need && tot <= 2048) {
        char* p = (char*)d_ws + aggB;
        u32* ghist = (u32*)p;
        u32* off   = ghist + tot;
        u32* gcur  = off + tot + 1;
        uint2* lists = (uint2*)((char*)d_ws + aggB + metaB);

        hipMemsetAsync(ghist, 0, (size_t)tot * sizeof(u32), stream);

        const int gB = (E + EPB - 1) / EPB;
        ghist_kernel<<<gB, 256, 0, stream>>>(edges, ghist, E, NB);
        scan_offsets<<<1, 1024, 0, stream>>>(ghist, off, gcur, tot);
        bin_kernel<<<gB, 256, 0, stream>>>(edges, ew, gcur, lists, E, NB);
        bucket_agg_kernel<<<tot * QSPLIT, 256, 0, stream>>>(nodes, lists, off,
                                                            agg_in, agg_out, N, NB);
    } else {
        // fallback: verified round-0 atomic scatter
        hipMemsetAsync(d_ws, 0, aggB, stream);
        long long ethreads = (long long)E * 16;
        int egrid = (int)((ethreads + 255) / 256);
        edge_scatter_fallback<<<egrid, 256, 0, stream>>>(nodes, edges, ew,
                                                         agg_in, agg_out, E);
    }

    int mgrid = (N + TN - 1) / TN;
    mlp_kernel<<<mgrid, 256, 0, stream>>>(agg_in, agg_out, nodes,
        W1, b1, g1, be1, W2, b2, g2, be2, W3, b3, g3, be3, W4, b4, g4, be4,
        (float*)d_out, N);
}

// Round 5
// 934.384 us; speedup vs baseline: 1.2491x; 1.0306x over previous
//
#include <hip/hip_runtime.h>
#include <stdint.h>

#define DIM 16
#define HID 128
#define TN  64            // nodes per block (MLP)
#define ROWF 132          // LDS row stride in floats (128 + 4 pad)
#define EPSF 1e-5f

#define BN   64           // nodes per bucket == agg tile (4 KB LDS)
#define EPB  8192         // edges per binning block
#define MAXTOT 3328       // max bucket-directions the LDS hists support

typedef unsigned int u32;

// NaN-free tanh; |x| <= ~12 here (LN output bounded by sqrt(H))
__device__ __forceinline__ float safe_tanh(float x) {
    float a = fabsf(x);
    float e = __expf(2.0f * a);
    float t = 1.0f - 2.0f / (e + 1.0f);
    return copysignf(t, x);
}

// ---------------- binned aggregation path ---------------------------------
// bucket of node n = n>>6 (64-node buckets). Bucket-direction index:
// in = (dst>>6), out = NB + (src>>6).
// Record: x = neighbor(17b) | local(6b)<<17, y = w bits.

__global__ void __launch_bounds__(256) ghist_kernel(
    const int* __restrict__ edges, u32* __restrict__ ghist, int E, int NB)
{
    __shared__ u32 h[MAXTOT];
    const int tid = threadIdx.x;
    const int tot = 2 * NB;
    for (int i = tid; i < tot; i += 256) h[i] = 0;
    __syncthreads();
    const int base = blockIdx.x * EPB;
    for (int i = tid; i < EPB; i += 256) {
        int e = base + i;
        if (e < E) {
            int src = edges[2 * e];
            int dst = edges[2 * e + 1];
            atomicAdd(&h[dst >> 6], 1u);
            atomicAdd(&h[NB + (src >> 6)], 1u);
        }
    }
    __syncthreads();
    for (int i = tid; i < tot; i += 256) {
        u32 c = h[i];
        if (c) atomicAdd(&ghist[i], c);
    }
}

// single-block exclusive scan: off[0..tot] (incl. total), gcur = copy
__global__ void __launch_bounds__(1024) scan_offsets(
    const u32* __restrict__ ghist, u32* __restrict__ off,
    u32* __restrict__ gcur, int tot)
{
    __shared__ u32 sm[1024];
    const int tid = threadIdx.x;
    u32 carry = 0;
    for (int b0 = 0; b0 < tot; b0 += 1024) {
        int i = b0 + tid;
        u32 v = (i < tot) ? ghist[i] : 0u;
        __syncthreads();
        sm[tid] = v;
        __syncthreads();
        for (int s = 1; s < 1024; s <<= 1) {
            u32 t = (tid >= s) ? sm[tid - s] : 0u;
            __syncthreads();
            sm[tid] += t;
            __syncthreads();
        }
        u32 excl = sm[tid] - v + carry;
        if (i < tot) { off[i] = excl; gcur[i] = excl; }
        carry += sm[1023];
    }
    if (tid == 0) off[tot] = carry;
}

// bin edges into bucket runs: one global cursor atomic per (block,bucket),
// records land in contiguous runs -> line-efficient writeback.
__global__ void __launch_bounds__(256) bin_kernel(
    const int* __restrict__ edges, const float* __restrict__ ew,
    u32* __restrict__ gcur, uint2* __restrict__ lists, int E, int NB)
{
    __shared__ u32 hcnt[MAXTOT];
    __shared__ u32 hbase[MAXTOT];
    const int tid = threadIdx.x;
    const int tot = 2 * NB;
    for (int i = tid; i < tot; i += 256) hcnt[i] = 0;
    __syncthreads();
    const int base = blockIdx.x * EPB;
    for (int i = tid; i < EPB; i += 256) {
        int e = base + i;
        if (e < E) {
            int src = edges[2 * e];
            int dst = edges[2 * e + 1];
            atomicAdd(&hcnt[dst >> 6], 1u);
            atomicAdd(&hcnt[NB + (src >> 6)], 1u);
        }
    }
    __syncthreads();
    for (int i = tid; i < tot; i += 256) {
        u32 c = hcnt[i];
        hbase[i] = c ? atomicAdd(&gcur[i], c) : 0u;
        hcnt[i] = 0;        // safe: all counting atomics done (barrier above)
    }
    __syncthreads();
    for (int i = tid; i < EPB; i += 256) {
        int e = base + i;
        if (e < E) {
            int src = edges[2 * e];
            int dst = edges[2 * e + 1];
            u32 wb = __float_as_uint(ew[e]);
            int b1 = dst >> 6;
            u32 r1 = atomicAdd(&hcnt[b1], 1u);
            lists[hbase[b1] + r1] =
                make_uint2((u32)src | ((u32)(dst & 63) << 17), wb);
            int b2 = NB + (src >> 6);
            u32 r2 = atomicAdd(&hcnt[b2], 1u);
            lists[hbase[b2] + r2] =
                make_uint2((u32)dst | ((u32)(src & 63) << 17), wb);
        }
    }
}

// one block per bucket-direction: every record in range belongs to this
// block's 64-node tile (no filter). 16 lanes per record (lane = component);
// 8-deep ILP keeps 8 independent list-load -> gather chains in flight.
__global__ void __launch_bounds__(256) bucket_agg_kernel(
    const float* __restrict__ nodes, const uint2* __restrict__ lists,
    const u32* __restrict__ off, float* __restrict__ agg_in,
    float* __restrict__ agg_out, int N, int NB)
{
    __shared__ float sagg[BN * DIM];   // 4 KB
    const int tid = threadIdx.x;
    const int bd = blockIdx.x;         // 0..2NB-1
    for (int i = tid; i < BN * DIM; i += 256) sagg[i] = 0.f;
    __syncthreads();

    const u32 s = off[bd], epos = off[bd + 1];
    const int c = tid & 15;

    u32 r = s + (tid >> 4);
    for (; r + 112 < epos; r += 128) {
        uint2 e[8];
        #pragma unroll
        for (int j = 0; j < 8; ++j) e[j] = lists[r + 16 * j];
        float v[8];
        #pragma unroll
        for (int j = 0; j < 8; ++j)
            v[j] = nodes[(e[j].x & 0x1FFFF) * DIM + c] * __uint_as_float(e[j].y);
        #pragma unroll
        for (int j = 0; j < 8; ++j)
            atomicAdd(&sagg[((e[j].x >> 17) & 63) * DIM + c], v[j]);
    }
    for (; r < epos; r += 16) {
        uint2 e0 = lists[r];
        float v = nodes[(e0.x & 0x1FFFF) * DIM + c] * __uint_as_float(e0.y);
        atomicAdd(&sagg[((e0.x >> 17) & 63) * DIM + c], v);
    }
    __syncthreads();

    const int bucket = (bd < NB) ? bd : bd - NB;
    float* dst = (bd < NB) ? agg_in : agg_out;
    const int nb0 = bucket * BN;
    // 64 rows x 16 f32 = 256 float4: exactly one per thread
    {
        int idx = tid * 4;
        int node = nb0 + (idx >> 4);
        if (node < N)
            *(float4*)&dst[(size_t)node * DIM + (idx & 15)] =
                *(float4*)&sagg[idx];
    }
}

// ---------------- fallback: fp32 atomic scatter (round-0, verified) -------
__global__ void __launch_bounds__(256) edge_scatter_fallback(
    const float* __restrict__ nodes, const int* __restrict__ edges,
    const float* __restrict__ ew, float* __restrict__ agg_in,
    float* __restrict__ agg_out, int nEdges)
{
    int gid = blockIdx.x * 256 + threadIdx.x;
    int e = gid >> 4;
    if (e >= nEdges) return;
    int c = gid & 15;
    int src = edges[2 * e];
    int dst = edges[2 * e + 1];
    float w  = ew[e];
    float vs = nodes[src * DIM + c];
    float vd = nodes[dst * DIM + c];
    atomicAdd(&agg_in[dst * DIM + c], vs * w);
    atomicAdd(&agg_out[src * DIM + c], vd * w);
}

// ---------------- Phase 2: fused 4-layer MLP (round-0, verified) ----------
template<int K>
__device__ __forceinline__ void dense_ln_tanh(
    const float* __restrict__ W, const float* __restrict__ bias,
    const float* __restrict__ g, const float* __restrict__ be,
    float (&X)[TN][ROWF], int tid)
{
    const int c0 = (tid & 31) * 4;   // column group: lanes 0..31 cover 128 cols
    const int n0 = (tid >> 5) * 8;   // row group: 8 rows per thread
    float acc[8][4];
    {
        float4 bv = *(const float4*)(bias + c0);
        #pragma unroll
        for (int i = 0; i < 8; ++i) {
            acc[i][0] = bv.x; acc[i][1] = bv.y; acc[i][2] = bv.z; acc[i][3] = bv.w;
        }
    }

    #pragma unroll 2
    for (int k = 0; k < K; k += 4) {
        float xr[8][4];
        #pragma unroll
        for (int i = 0; i < 8; ++i) {
            float4 t = *(const float4*)&X[n0 + i][k];
            xr[i][0] = t.x; xr[i][1] = t.y; xr[i][2] = t.z; xr[i][3] = t.w;
        }
        float w[4][4];
        #pragma unroll
        for (int kk = 0; kk < 4; ++kk) {
            float4 t = *(const float4*)(W + (k + kk) * HID + c0);
            w[kk][0] = t.x; w[kk][1] = t.y; w[kk][2] = t.z; w[kk][3] = t.w;
        }
        #pragma unroll
        for (int kk = 0; kk < 4; ++kk)
            #pragma unroll
            for (int i = 0; i < 8; ++i)
                #pragma unroll
                for (int j = 0; j < 4; ++j) acc[i][j] += xr[i][kk] * w[kk][j];
    }

    float s[8], q[8];
    #pragma unroll
    for (int i = 0; i < 8; ++i) {
        s[i] = acc[i][0] + acc[i][1] + acc[i][2] + acc[i][3];
        q[i] = acc[i][0]*acc[i][0] + acc[i][1]*acc[i][1]
             + acc[i][2]*acc[i][2] + acc[i][3]*acc[i][3];
    }
    #pragma unroll
    for (int m = 1; m <= 16; m <<= 1) {
        #pragma unroll
        for (int i = 0; i < 8; ++i) {
            s[i] += __shfl_xor(s[i], m);
            q[i] += __shfl_xor(q[i], m);
        }
    }

    float4 gv  = *(const float4*)(g + c0);
    float4 bev = *(const float4*)(be + c0);
    float gr[4]  = {gv.x, gv.y, gv.z, gv.w};
    float ber[4] = {bev.x, bev.y, bev.z, bev.w};

    __syncthreads();   // all X reads of this layer complete before overwrite
    #pragma unroll
    for (int i = 0; i < 8; ++i) {
        float mean = s[i] * (1.0f / HID);
        float var  = fmaxf(q[i] * (1.0f / HID) - mean * mean, 0.0f);
        float r = rsqrtf(var + EPSF);
        float o[4];
        #pragma unroll
        for (int j = 0; j < 4; ++j)
            o[j] = safe_tanh((acc[i][j] - mean) * r * gr[j] + ber[j]);
        *(float4*)&X[n0 + i][c0] = make_float4(o[0], o[1], o[2], o[3]);
    }
    __syncthreads();
}

__global__ void __launch_bounds__(256, 3) mlp_kernel(
    const float* __restrict__ agg_in, const float* __restrict__ agg_out,
    const float* __restrict__ nodes,
    const float* __restrict__ W1, const float* __restrict__ b1, const float* __restrict__ g1, const float* __restrict__ be1,
    const float* __restrict__ W2, const float* __restrict__ b2, const float* __restrict__ g2, const float* __restrict__ be2,
    const float* __restrict__ W3, const float* __restrict__ b3, const float* __restrict__ g3, const float* __restrict__ be3,
    const float* __restrict__ W4, const float* __restrict__ b4, const float* __restrict__ g4, const float* __restrict__ be4,
    float* __restrict__ out, int nNodes)
{
    __shared__ float X[TN][ROWF];

    const int tid = threadIdx.x;
    const int node0 = blockIdx.x * TN;

    // stage x = concat(agg_in, agg_out, nodes): 64 rows x 12 float4
    for (int i = tid; i < TN * 12; i += 256) {
        int n = i / 12, c4 = i - n * 12;
        int gn = node0 + n;
        float4 v = make_float4(0.f, 0.f, 0.f, 0.f);
        if (gn < nNodes) {
            if (c4 < 4)      v = *(const float4*)(agg_in  + (size_t)gn * DIM + c4 * 4);
            else if (c4 < 8) v = *(const float4*)(agg_out + (size_t)gn * DIM + (c4 - 4) * 4);
            else             v = *(const float4*)(nodes   + (size_t)gn * DIM + (c4 - 8) * 4);
        }
        *(float4*)&X[n][c4 * 4] = v;
    }
    __syncthreads();

    dense_ln_tanh<48>(W1, b1, g1, be1, X, tid);
    dense_ln_tanh<128>(W2, b2, g2, be2, X, tid);
    dense_ln_tanh<128>(W3, b3, g3, be3, X, tid);

    // Layer 4: 128 -> 16, LN over 16, tanh, store fp32
    {
        const int c2 = tid & 15;
        const int nb = tid >> 4;   // 0..15; handles nodes nb + {0,16,32,48}
        float a[4];
        {
            float bv = b4[c2];
            #pragma unroll
            for (int t = 0; t < 4; ++t) a[t] = bv;
        }
        #pragma unroll 2
        for (int k = 0; k < HID; k += 4) {
            float w[4];
            #pragma unroll
            for (int kk = 0; kk < 4; ++kk) w[kk] = W4[(k + kk) * DIM + c2];
            #pragma unroll
            for (int t = 0; t < 4; ++t) {
                float4 x = *(const float4*)&X[nb + 16 * t][k];
                a[t] += x.x * w[0] + x.y * w[1] + x.z * w[2] + x.w * w[3];
            }
        }
        float s[4], q[4];
        #pragma unroll
        for (int t = 0; t < 4; ++t) { s[t] = a[t]; q[t] = a[t] * a[t]; }
        #pragma unroll
        for (int m = 1; m <= 8; m <<= 1) {
            #pragma unroll
            for (int t = 0; t < 4; ++t) {
                s[t] += __shfl_xor(s[t], m);
                q[t] += __shfl_xor(q[t], m);
            }
        }
        float g4v = g4[c2], be4v = be4[c2];
        #pragma unroll
        for (int t = 0; t < 4; ++t) {
            int node = node0 + nb + 16 * t;
            if (node < nNodes) {
                float mean = s[t] * (1.0f / DIM);
                float var  = fmaxf(q[t] * (1.0f / DIM) - mean * mean, 0.0f);
                float o = safe_tanh((a[t] - mean) * rsqrtf(var + EPSF) * g4v + be4v);
                out[(size_t)node * DIM + c2] = o;
            }
        }
    }
}

extern "C" void kernel_launch(void* const* d_in, const int* in_sizes, int n_in,
                              void* d_out, int out_size, void* d_ws, size_t ws_size,
                              hipStream_t stream)
{
    const float* nodes = (const float*)d_in[0];
    const int*   edges = (const int*)d_in[1];
    const float* ew    = (const float*)d_in[2];
    const float *W1 = (const float*)d_in[3],  *b1 = (const float*)d_in[4],
                *g1 = (const float*)d_in[5],  *be1 = (const float*)d_in[6];
    const float *W2 = (const float*)d_in[7],  *b2 = (const float*)d_in[8],
                *g2 = (const float*)d_in[9],  *be2 = (const float*)d_in[10];
    const float *W3 = (const float*)d_in[11], *b3 = (const float*)d_in[12],
                *g3 = (const float*)d_in[13], *be3 = (const float*)d_in[14];
    const float *W4 = (const float*)d_in[15], *b4 = (const float*)d_in[16],
                *g4 = (const float*)d_in[17], *be4 = (const float*)d_in[18];

    const int N = in_sizes[0] / DIM;     // 100000
    const int E = in_sizes[2];           // 3200000

    const int NB  = (N + BN - 1) / BN;   // 1563
    const int tot = 2 * NB;              // 3126

    // workspace layout:
    //   agg_in/agg_out : 2*N*DIM f32
    //   ghist (tot) | off (tot+1) | gcur (tot)  u32, padded to 256B
    //   lists : 2E uint2
    const size_t aggB   = (size_t)2 * N * DIM * sizeof(float);
    const size_t metaB  = (((size_t)(3 * tot + 1) * sizeof(u32)) + 255) & ~(size_t)255;
    const size_t listsB = (size_t)2 * E * sizeof(uint2);
    const size_t need   = aggB + metaB + listsB;

    float* agg_in  = (float*)d_ws;
    float* agg_out = agg_in + (size_t)N * DIM;

    if (ws_size >= need && tot <= MAXTOT && N < (1 << 17)) {
        char* p = (char*)d_ws + aggB;
        u32* ghist = (u32*)p;
        u32* off   = ghist + tot;
        u32* gcur  = off + tot + 1;
        uint2* lists = (uint2*)((char*)d_ws + aggB + metaB);

        hipMemsetAsync(ghist, 0, (size_t)tot * sizeof(u32), stream);

        const int gB = (E + EPB - 1) / EPB;
        ghist_kernel<<<gB, 256, 0, stream>>>(edges, ghist, E, NB);
        scan_offsets<<<1, 1024, 0, stream>>>(ghist, off, gcur, tot);
        bin_kernel<<<gB, 256, 0, stream>>>(edges, ew, gcur, lists, E, NB);
        bucket_agg_kernel<<<tot, 256, 0, stream>>>(nodes, lists, off,
                                                   agg_in, agg_out, N, NB);
    } else {
        // fallback: verified round-0 atomic scatter
        hipMemsetAsync(d_ws, 0, aggB, stream);
        long long ethreads = (long long)E * 16;
        int egrid = (int)((ethreads + 255) / 256);
        edge_scatter_fallback<<<egrid, 256, 0, stream>>>(nodes, edges, ew,
                                                         agg_in, agg_out, E);
    }

    int mgrid = (N + TN - 1) / TN;
    mlp_kernel<<<mgrid, 256, 0, stream>>>(agg_in, agg_out, nodes,
        W1, b1, g1, be1, W2, b2, g2, be2, W3, b3, g3, be3, W4, b4, g4, be4,
        (float*)d_out, N);
}